// Round 3
// baseline (252.112 us; speedup 1.0000x reference)
//
#include <hip/hip_runtime.h>
#include <hip/hip_cooperative_groups.h>
#include <cstdint>

namespace cg = cooperative_groups;

// ECT loss, exact formulation (R1 math, absmax 0.0), one cooperative dispatch.
// A[bc][r][d] = sum_p dw[b,p,c] * sigmoid(8*(lin_r - <x_p, v_d>)),  c in {0,1};
// c=2 = -(c0+c1). loss = mean over 12288 incl. reconstructed c2.
//
// Grid 512 = 8 d-groups (4 dirs) x 64 voxel-chunks (1728 voxels).
// Thread (d_loc = t>>6, r = t&63) accumulates 4 bc values over the chunk.
// gacc layout: idx = (r*32 + d)*4 + bc, bc = b*2 + c.  (8192 floats in ws)

#define P_TOT 110592

__device__ __forceinline__ uint32_t rotl32(uint32_t x, int d) {
  return (x << d) | (x >> (32 - d));
}

// threefry2x32, key = (0,17) — bit-exact vs jax (verified R1/R2)
__device__ __forceinline__ void threefry_0_17(uint32_t x0, uint32_t x1,
                                              uint32_t& o0, uint32_t& o1) {
  const uint32_t ks0 = 0u, ks1 = 17u, ks2 = 0x1BD11BDAu ^ 0u ^ 17u;
  x0 += ks0; x1 += ks1;
#define R4(a,b,c,dd) \
  x0 += x1; x1 = rotl32(x1,(a)); x1 ^= x0; \
  x0 += x1; x1 = rotl32(x1,(b)); x1 ^= x0; \
  x0 += x1; x1 = rotl32(x1,(c)); x1 ^= x0; \
  x0 += x1; x1 = rotl32(x1,(dd)); x1 ^= x0;
  R4(13,15,26,6)   x0 += ks1; x1 += ks2 + 1u;
  R4(17,29,16,24)  x0 += ks2; x1 += ks0 + 2u;
  R4(13,15,26,6)   x0 += ks0; x1 += ks1 + 3u;
  R4(17,29,16,24)  x0 += ks1; x1 += ks2 + 4u;
  R4(13,15,26,6)   x0 += ks2; x1 += ks0 + 5u;
#undef R4
  o0 = x0; o1 = x1;
}

// XLA ErfInv32 — bit-exact vs jax (verified R1/R2)
__device__ __forceinline__ float erfinv_f32(float x) {
  float w = -log1pf(-x * x);
  float p;
  if (w < 5.0f) {
    w = w - 2.5f;
    p = 2.81022636e-08f;
    p = fmaf(p, w, 3.43273939e-07f);
    p = fmaf(p, w, -3.5233877e-06f);
    p = fmaf(p, w, -4.39150654e-06f);
    p = fmaf(p, w, 0.00021858087f);
    p = fmaf(p, w, -0.00125372503f);
    p = fmaf(p, w, -0.00417768164f);
    p = fmaf(p, w, 0.246640727f);
    p = fmaf(p, w, 1.50140941f);
  } else {
    w = sqrtf(w) - 3.0f;
    p = -0.000200214257f;
    p = fmaf(p, w, 0.000100950558f);
    p = fmaf(p, w, 0.00134934322f);
    p = fmaf(p, w, 0.000337081863f);
    p = fmaf(p, w, 0.00573950773f);
    p = fmaf(p, w, -0.0076224613f);
    p = fmaf(p, w, 0.00943887047f);
    p = fmaf(p, w, 1.00167406f);
    p = fmaf(p, w, 2.83297682f);
  }
  return p * x;
}

__global__ __launch_bounds__(256, 2) void ect_all(
    const float* __restrict__ pred, const int* __restrict__ tgt,
    float* __restrict__ gacc, float* __restrict__ out) {
  __shared__ float dirs[96];          // [3][32] unit directions
  __shared__ float E_lds[2][4][64];   // double-buffered exp(8*nh) per (d_loc, v)
  __shared__ float4 dw_lds[1728];     // (b0c0,b0c1,b1c0,b1c1) per chunk voxel

  cg::grid_group grid = cg::this_grid();
  const int t = threadIdx.x;
  const int bx = blockIdx.x;
  const int dgrp = bx & 7;
  const int chunk = bx >> 3;
  const int d_loc = t >> 6;           // 0..3 (= wave id)
  const int r = t & 63;

  // ---- phase 0: zero accumulators & output ----
  if (bx < 32) gacc[bx * 256 + t] = 0.0f;
  if (bx == 32 && t == 0) out[0] = 0.0f;
  grid.sync();

  // ---- block init: directions ----
  if (t < 96) {
    uint32_t o0, o1;
    threefry_0_17(0u, (uint32_t)t, o0, o1);
    uint32_t bits = o0 ^ o1;
    float u = __uint_as_float((bits >> 9) | 0x3F800000u) - 1.0f;
    const float lo = -0.99999994f;
    float v = fmaf(u, 2.0f, lo);
    v = fmaxf(v, lo);
    dirs[t] = 1.41421356237f * erfinv_f32(v);
  }
  __syncthreads();
  if (t < 32) {
    float a = dirs[t], b = dirs[32 + t], c = dirs[64 + t];
    float n = fmaxf(sqrtf(a * a + b * b + c * c), 1e-12f);
    dirs[t] = a / n; dirs[32 + t] = b / n; dirs[64 + t] = c / n;
  }

  // ---- block init: dw for the chunk's 1728 voxels (softmax - onehot) ----
  const int cbase = chunk * 1728;
  for (int i = t; i < 1728; i += 256) {
    int p = cbase + i;
    float w[4];
#pragma unroll
    for (int b = 0; b < 2; b++) {
      const float* pb = pred + b * (3 * P_TOT) + p;
      float x0 = pb[0], x1 = pb[P_TOT], x2 = pb[2 * P_TOT];
      float m = fmaxf(x0, fmaxf(x1, x2));
      float e0 = __expf(x0 - m), e1 = __expf(x1 - m), e2 = __expf(x2 - m);
      float inv = 1.0f / (e0 + e1 + e2);
      int tg = tgt[b * P_TOT + p];
      w[b * 2 + 0] = e0 * inv - ((tg == 0) ? 1.0f : 0.0f);
      w[b * 2 + 1] = e1 * inv - ((tg == 1) ? 1.0f : 0.0f);
    }
    dw_lds[i] = float4{w[0], w[1], w[2], w[3]};
  }
  __syncthreads();

  // per-thread constants
  const int d = dgrp * 4 + d_loc;
  const float radius = 1.1f * 1.7320508075688772f;
  const float step = (2.0f * radius) / 63.0f;
  const float lin = fmaf((float)r, step, -radius);
  const float K = __expf(-8.0f * lin);
  const float da0 = dirs[(t & 31) /*placeholder avoid unused*/ * 0 + (dgrp * 4 + (t >> 6))];
  const float dir0 = dirs[d], dir1 = dirs[32 + d], dir2 = dirs[64 + d];
  (void)da0;

  // phase A helper values for E tasks: this thread computes E for (d_a, v_a)
  const int v_a = t & 63;
  const int d_a = t >> 6;  // same as d_loc
  const float ed0 = dir0, ed1 = dir1, ed2 = dir2;  // d_a == d_loc => same dir
  (void)ed0; (void)ed1; (void)ed2;

  float2 acc01 = {0.0f, 0.0f};
  float2 acc23 = {0.0f, 0.0f};

  // phase A for round 0
  {
    int p = cbase + v_a;
    int ix = p / 2304; int rem = p - ix * 2304;
    int iy = rem / 48; int iz = rem - iy * 48;
    const float delta = 2.0f / 47.0f;
    float cx = (float)ix * delta - 1.0f;
    float cy = (float)iy * delta - 1.0f;
    float cz = (float)iz * delta - 1.0f;
    float nh = fmaf(cz, dir2, fmaf(cy, dir1, cx * dir0));
    E_lds[0][d_a][v_a] = __expf(8.0f * nh);
  }
  __syncthreads();

  // ---- main loop: 27 rounds x 64 voxels ----
  for (int ro = 0; ro < 27; ro++) {
    if (ro < 26) {  // phase A for next round into other buffer
      int p = cbase + (ro + 1) * 64 + v_a;
      int ix = p / 2304; int rem = p - ix * 2304;
      int iy = rem / 48; int iz = rem - iy * 48;
      const float delta = 2.0f / 47.0f;
      float cx = (float)ix * delta - 1.0f;
      float cy = (float)iy * delta - 1.0f;
      float cz = (float)iz * delta - 1.0f;
      float nh = fmaf(cz, dir2, fmaf(cy, dir1, cx * dir0));
      E_lds[(ro + 1) & 1][d_a][v_a] = __expf(8.0f * nh);
    }
    // phase B: consume 64 voxels for (d_loc, r)
    const float* Erow = &E_lds[ro & 1][d_loc][0];
    const int vbase = ro * 64;
#pragma unroll 4
    for (int g = 0; g < 16; g++) {
      float4 e4 = *reinterpret_cast<const float4*>(Erow + g * 4);
      float4 w0 = dw_lds[vbase + g * 4 + 0];
      float4 w1 = dw_lds[vbase + g * 4 + 1];
      float4 w2 = dw_lds[vbase + g * 4 + 2];
      float4 w3 = dw_lds[vbase + g * 4 + 3];
      float z0 = fmaf(e4.x, K, 1.0f);
      float z1 = fmaf(e4.y, K, 1.0f);
      float z2 = fmaf(e4.z, K, 1.0f);
      float z3 = fmaf(e4.w, K, 1.0f);
      // paired reciprocal: z in [1, ~4e12], product < 1.6e25 (no overflow)
      float p01 = z0 * z1, p23 = z2 * z3;
      float r01 = __builtin_amdgcn_rcpf(p01);
      float r23 = __builtin_amdgcn_rcpf(p23);
      float s0 = z1 * r01, s1 = z0 * r01;
      float s2 = z3 * r23, s3 = z2 * r23;
      acc01.x = fmaf(w0.x, s0, acc01.x); acc01.y = fmaf(w0.y, s0, acc01.y);
      acc23.x = fmaf(w0.z, s0, acc23.x); acc23.y = fmaf(w0.w, s0, acc23.y);
      acc01.x = fmaf(w1.x, s1, acc01.x); acc01.y = fmaf(w1.y, s1, acc01.y);
      acc23.x = fmaf(w1.z, s1, acc23.x); acc23.y = fmaf(w1.w, s1, acc23.y);
      acc01.x = fmaf(w2.x, s2, acc01.x); acc01.y = fmaf(w2.y, s2, acc01.y);
      acc23.x = fmaf(w2.z, s2, acc23.x); acc23.y = fmaf(w2.w, s2, acc23.y);
      acc01.x = fmaf(w3.x, s3, acc01.x); acc01.y = fmaf(w3.y, s3, acc01.y);
      acc23.x = fmaf(w3.z, s3, acc23.x); acc23.y = fmaf(w3.w, s3, acc23.y);
    }
    __syncthreads();
  }

  // ---- epilogue: accumulate into global (524k atomics total) ----
  {
    int base = (r * 32 + d) * 4;
    atomicAdd(&gacc[base + 0], acc01.x);
    atomicAdd(&gacc[base + 1], acc01.y);
    atomicAdd(&gacc[base + 2], acc23.x);
    atomicAdd(&gacc[base + 3], acc23.y);
  }
  __threadfence();
  grid.sync();

  // ---- finalize: loss = mean over 12288 incl. c2 = -(c0+c1) ----
  if (bx < 16) {
    int gi = bx * 256 + t;           // 0..4095 = (b, r, d)
    int b = gi >> 11;
    int rd = gi & 2047;
    int base = rd * 4 + b * 2;
    float a0 = gacc[base], a1 = gacc[base + 1];
    float s = a0 * a0 + a1 * a1 + (a0 + a1) * (a0 + a1);
#pragma unroll
    for (int off = 32; off > 0; off >>= 1) s += __shfl_down(s, off, 64);
    if ((t & 63) == 0) atomicAdd(out, s * (1.0f / 12288.0f));
  }
}

extern "C" void kernel_launch(void* const* d_in, const int* in_sizes, int n_in,
                              void* d_out, int out_size, void* d_ws, size_t ws_size,
                              hipStream_t stream) {
  const float* pred = (const float*)d_in[0];
  const int* tgt = (const int*)d_in[1];
  float* gacc = (float*)d_ws;          // 8192 floats = 32 KB
  float* out = (float*)d_out;

  void* args[] = {(void*)&pred, (void*)&tgt, (void*)&gacc, (void*)&out};
  hipLaunchCooperativeKernel((const void*)ect_all, dim3(512), dim3(256),
                             args, 0, stream);
}

// Round 4
// 147.623 us; speedup vs baseline: 1.7078x; 1.7078x over previous
//
#include <hip/hip_runtime.h>
#include <cstdint>

// ECT loss, exact elementwise formulation (R1 math, absmax 0.0).
// A[bc][r][d] = sum_p dw[b,p,c] * sigmoid(8*(lin_r - <x_p, v_d>)), c in {0,1};
// c2 = -(c0+c1); loss = mean over 12288.
//
// ect_main: grid 512 x 256 thr. Block owns 216 voxels; thread (d = t&31,
// rg = t>>5) owns (d, r = rg*8..rg*8+7) x 4 bc = 32 accumulators.
// NO barriers in the main loop: each thread computes its own exp(8*nh) from
// LDS-cached coords (R3 was LDS-pipe bound + barrier bound; this is VALU bound).
// Epilogue: 32 scatter-atomics per thread into gacc replica (blockIdx & 3).
//
// ws: gacc[4][8192] floats = 128 KB.

#define P_TOT 110592
#define VOX 216
#define NREP 4

__device__ __forceinline__ uint32_t rotl32(uint32_t x, int d) {
  return (x << d) | (x >> (32 - d));
}

// threefry2x32, key = (0,17) — bit-exact vs jax (verified R1-R3)
__device__ __forceinline__ void threefry_0_17(uint32_t x0, uint32_t x1,
                                              uint32_t& o0, uint32_t& o1) {
  const uint32_t ks0 = 0u, ks1 = 17u, ks2 = 0x1BD11BDAu ^ 0u ^ 17u;
  x0 += ks0; x1 += ks1;
#define R4(a,b,c,dd) \
  x0 += x1; x1 = rotl32(x1,(a)); x1 ^= x0; \
  x0 += x1; x1 = rotl32(x1,(b)); x1 ^= x0; \
  x0 += x1; x1 = rotl32(x1,(c)); x1 ^= x0; \
  x0 += x1; x1 = rotl32(x1,(dd)); x1 ^= x0;
  R4(13,15,26,6)   x0 += ks1; x1 += ks2 + 1u;
  R4(17,29,16,24)  x0 += ks2; x1 += ks0 + 2u;
  R4(13,15,26,6)   x0 += ks0; x1 += ks1 + 3u;
  R4(17,29,16,24)  x0 += ks1; x1 += ks2 + 4u;
  R4(13,15,26,6)   x0 += ks2; x1 += ks0 + 5u;
#undef R4
  o0 = x0; o1 = x1;
}

// XLA ErfInv32 — bit-exact vs jax (verified R1-R3)
__device__ __forceinline__ float erfinv_f32(float x) {
  float w = -log1pf(-x * x);
  float p;
  if (w < 5.0f) {
    w = w - 2.5f;
    p = 2.81022636e-08f;
    p = fmaf(p, w, 3.43273939e-07f);
    p = fmaf(p, w, -3.5233877e-06f);
    p = fmaf(p, w, -4.39150654e-06f);
    p = fmaf(p, w, 0.00021858087f);
    p = fmaf(p, w, -0.00125372503f);
    p = fmaf(p, w, -0.00417768164f);
    p = fmaf(p, w, 0.246640727f);
    p = fmaf(p, w, 1.50140941f);
  } else {
    w = sqrtf(w) - 3.0f;
    p = -0.000200214257f;
    p = fmaf(p, w, 0.000100950558f);
    p = fmaf(p, w, 0.00134934322f);
    p = fmaf(p, w, 0.000337081863f);
    p = fmaf(p, w, 0.00573950773f);
    p = fmaf(p, w, -0.0076224613f);
    p = fmaf(p, w, 0.00943887047f);
    p = fmaf(p, w, 1.00167406f);
    p = fmaf(p, w, 2.83297682f);
  }
  return p * x;
}

__global__ __launch_bounds__(256, 2) void ect_main(
    const float* __restrict__ pred, const int* __restrict__ tgt,
    float* __restrict__ gacc) {
  __shared__ float dirs[96];        // [3][32] unit directions
  __shared__ float4 voxdw[VOX];     // (b0c0,b0c1,b1c0,b1c1)
  __shared__ float4 voxc[VOX];      // (cx,cy,cz,-)

  const int t = threadIdx.x;
  const int bx = blockIdx.x;
  const int d = t & 31;
  const int rg = t >> 5;
  const int cbase = bx * VOX;

  // ---- init: directions (raw normals) ----
  if (t < 96) {
    uint32_t o0, o1;
    threefry_0_17(0u, (uint32_t)t, o0, o1);
    uint32_t bits = o0 ^ o1;
    float u = __uint_as_float((bits >> 9) | 0x3F800000u) - 1.0f;
    const float lo = -0.99999994f;
    float v = fmaf(u, 2.0f, lo);
    v = fmaxf(v, lo);
    dirs[t] = 1.41421356237f * erfinv_f32(v);
  }
  __syncthreads();
  if (t < 32) {
    float a = dirs[t], b = dirs[32 + t], c = dirs[64 + t];
    float n = fmaxf(sqrtf(a * a + b * b + c * c), 1e-12f);
    dirs[t] = a / n; dirs[32 + t] = b / n; dirs[64 + t] = c / n;
  }
  // ---- init: per-voxel dw (softmax - onehot) and coords ----
  if (t < VOX) {
    int p = cbase + t;
    int ix = p / 2304; int rem = p - ix * 2304;
    int iy = rem / 48; int iz = rem - iy * 48;
    const float delta = 2.0f / 47.0f;
    voxc[t] = float4{(float)ix * delta - 1.0f, (float)iy * delta - 1.0f,
                     (float)iz * delta - 1.0f, 0.0f};
    float w[4];
#pragma unroll
    for (int b = 0; b < 2; b++) {
      const float* pb = pred + b * (3 * P_TOT) + p;
      float x0 = pb[0], x1 = pb[P_TOT], x2 = pb[2 * P_TOT];
      float m = fmaxf(x0, fmaxf(x1, x2));
      float e0 = __expf(x0 - m), e1 = __expf(x1 - m), e2 = __expf(x2 - m);
      float inv = 1.0f / (e0 + e1 + e2);
      int tg = tgt[b * P_TOT + p];
      w[b * 2 + 0] = e0 * inv - ((tg == 0) ? 1.0f : 0.0f);
      w[b * 2 + 1] = e1 * inv - ((tg == 1) ? 1.0f : 0.0f);
    }
    voxdw[t] = float4{w[0], w[1], w[2], w[3]};
  }
  __syncthreads();

  // per-thread constants
  const float dir0 = dirs[d], dir1 = dirs[32 + d], dir2 = dirs[64 + d];
  const float radius = 1.1f * 1.7320508075688772f;
  const float step = (2.0f * radius) / 63.0f;
  float K[8];
#pragma unroll
  for (int j = 0; j < 8; j++) {
    float lin = fmaf((float)(rg * 8 + j), step, -radius);
    K[j] = __expf(-8.0f * lin);
  }

  float acc[8][4];
#pragma unroll
  for (int j = 0; j < 8; j++)
#pragma unroll
    for (int bc = 0; bc < 4; bc++) acc[j][bc] = 0.0f;

  // ---- main loop: barrier-free, VALU-bound ----
#pragma unroll 4
  for (int v = 0; v < VOX; v++) {
    float4 c = voxc[v];
    float4 w = voxdw[v];
    float nh = fmaf(c.z, dir2, fmaf(c.y, dir1, c.x * dir0));
    float E = __expf(8.0f * nh);              // <= e^13.9, no overflow
    float z[8];
#pragma unroll
    for (int j = 0; j < 8; j++) z[j] = fmaf(E, K[j], 1.0f);  // 1..4.4e12
#pragma unroll
    for (int h = 0; h < 4; h++) {
      // paired reciprocal: product <= 2e25, no overflow
      float pz = z[2 * h] * z[2 * h + 1];
      float rr = __builtin_amdgcn_rcpf(pz);
      float s0 = z[2 * h + 1] * rr;           // sigmoid for r = rg*8+2h
      float s1 = z[2 * h] * rr;               // sigmoid for r = rg*8+2h+1
      acc[2 * h][0] = fmaf(w.x, s0, acc[2 * h][0]);
      acc[2 * h][1] = fmaf(w.y, s0, acc[2 * h][1]);
      acc[2 * h][2] = fmaf(w.z, s0, acc[2 * h][2]);
      acc[2 * h][3] = fmaf(w.w, s0, acc[2 * h][3]);
      acc[2 * h + 1][0] = fmaf(w.x, s1, acc[2 * h + 1][0]);
      acc[2 * h + 1][1] = fmaf(w.y, s1, acc[2 * h + 1][1]);
      acc[2 * h + 1][2] = fmaf(w.z, s1, acc[2 * h + 1][2]);
      acc[2 * h + 1][3] = fmaf(w.w, s1, acc[2 * h + 1][3]);
    }
  }

  // ---- epilogue: scatter-atomic into replica ----
  float* grep = gacc + (size_t)(bx & (NREP - 1)) * 8192;
#pragma unroll
  for (int j = 0; j < 8; j++) {
    int base = ((rg * 8 + j) * 32 + d) * 4;
    atomicAdd(&grep[base + 0], acc[j][0]);
    atomicAdd(&grep[base + 1], acc[j][1]);
    atomicAdd(&grep[base + 2], acc[j][2]);
    atomicAdd(&grep[base + 3], acc[j][3]);
  }
}

__global__ __launch_bounds__(256) void ect_fin(
    const float* __restrict__ gacc, float* __restrict__ out) {
  __shared__ float red[4];
  int t = threadIdx.x;
  float s = 0.0f;
  for (int i = t; i < 2048; i += 256) {       // i = r*32 + d
    float a0 = 0.f, a1 = 0.f, a2 = 0.f, a3 = 0.f;
#pragma unroll
    for (int rep = 0; rep < NREP; rep++) {
      const float4 g = *(const float4*)(gacc + (size_t)rep * 8192 + i * 4);
      a0 += g.x; a1 += g.y; a2 += g.z; a3 += g.w;
    }
    s += a0 * a0 + a1 * a1 + (a0 + a1) * (a0 + a1)
       + a2 * a2 + a3 * a3 + (a2 + a3) * (a2 + a3);
  }
#pragma unroll
  for (int off = 32; off > 0; off >>= 1) s += __shfl_down(s, off, 64);
  if ((t & 63) == 0) red[t >> 6] = s;
  __syncthreads();
  if (t == 0) out[0] = (red[0] + red[1] + red[2] + red[3]) * (1.0f / 12288.0f);
}

extern "C" void kernel_launch(void* const* d_in, const int* in_sizes, int n_in,
                              void* d_out, int out_size, void* d_ws, size_t ws_size,
                              hipStream_t stream) {
  const float* pred = (const float*)d_in[0];
  const int* tgt = (const int*)d_in[1];
  float* gacc = (float*)d_ws;                  // 4 * 8192 floats = 128 KB
  float* out = (float*)d_out;

  hipMemsetAsync(gacc, 0, (size_t)NREP * 8192 * sizeof(float), stream);
  hipLaunchKernelGGL(ect_main, dim3(512), dim3(256), 0, stream, pred, tgt, gacc);
  hipLaunchKernelGGL(ect_fin, dim3(1), dim3(256), 0, stream, gacc, out);
}